// Round 1
// 212.302 us; speedup vs baseline: 1.0167x; 1.0167x over previous
//
#include <hip/hip_runtime.h>
#include <hip/hip_bf16.h>
#include <cstdint>
#include <cstddef>

// Problem constants
#define BB 2
#define SS 2048
#define DD 1024
#define HH 16
#define HD 64

typedef __attribute__((ext_vector_type(8))) short bf16x8;
typedef __attribute__((ext_vector_type(4))) short bf16x4;
typedef __attribute__((ext_vector_type(4))) float f32x4;

// 16x16x16 bf16 MFMA (canonical _1k spelling; 4 bf16 per A/B operand)
#define MFMA16(va, vb, c) __builtin_amdgcn_mfma_f32_16x16x16bf16_1k(va, vb, c, 0, 0, 0)

// async global->LDS, 16B per lane, dest = wave-uniform base + lane*16
#define GLL(g, l) __builtin_amdgcn_global_load_lds( \
    (const __attribute__((address_space(1))) void*)(g), \
    (__attribute__((address_space(3))) void*)(l), 16, 0, 0)

// fast RTNE f32->bf16 (inputs guaranteed non-NaN in this problem)
__device__ __forceinline__ short f2bf_fast(float f) {
    uint32_t u = __float_as_uint(f);
    u += 0x7FFF + ((u >> 16) & 1);
    return (short)(u >> 16);
}
__device__ __forceinline__ uint32_t pack_bf2(float a, float b) {
    uint32_t ua = __float_as_uint(a), ub = __float_as_uint(b);
    ua += 0x7FFF + ((ua >> 16) & 1);
    ub += 0x7FFF + ((ub >> 16) & 1);
    return (ua >> 16) | (ub & 0xFFFF0000u);
}
// 8 fp32 -> 8 bf16 via two float4 loads, packed
__device__ __forceinline__ bf16x8 cvt8(const float* __restrict__ p) {
    float4 a = *(const float4*)p;
    float4 b = *(const float4*)(p + 4);
    union { uint32_t d[4]; bf16x8 v; } r;
    r.d[0] = pack_bf2(a.x, a.y);
    r.d[1] = pack_bf2(a.z, a.w);
    r.d[2] = pack_bf2(b.x, b.y);
    r.d[3] = pack_bf2(b.z, b.w);
    return r.v;
}

// ---------------- fp32 -> bf16 pre-convert (6 tensors, one dispatch) --------
__global__ __launch_bounds__(256) void cvt6_kernel(
    const float* __restrict__ s0, const float* __restrict__ s1,
    const float* __restrict__ s2, const float* __restrict__ s3,
    const float* __restrict__ s4, const float* __restrict__ s5,
    short* __restrict__ d0, short* __restrict__ d1, short* __restrict__ d2,
    short* __restrict__ d3, short* __restrict__ d4, short* __restrict__ d5)
{
    const int z = blockIdx.z;
    const float* s = (z == 0) ? s0 : (z == 1) ? s1 : (z == 2) ? s2
                   : (z == 3) ? s3 : (z == 4) ? s4 : s5;
    short* d = (z == 0) ? d0 : (z == 1) ? d1 : (z == 2) ? d2
             : (z == 3) ? d3 : (z == 4) ? d4 : d5;
    const int n8 = (z < 2) ? (BB * SS * DD / 8) : (DD * DD / 8);
    const int id = blockIdx.x * 256 + threadIdx.x;
    if (id >= n8) return;
    bf16x8 r = cvt8(s + (size_t)id * 8);
    *(uint4*)(d + (size_t)id * 8) = *(uint4*)&r;
}

// ---------------- fused QKV GEMM: 128x128 tile, z selects Q/K/V -------------
// z=0: Q -> [B,H,S,HD]; z=1: K -> [B,H,S,HD]; z=2: V -> [B,H,HD,S] (transposed)
template<int BF>
__global__ __launch_bounds__(256, 3) void qkv_gemm_kernel(
    const void* __restrict__ dec, const void* __restrict__ enc,
    const void* __restrict__ Wq, const void* __restrict__ Wk,
    const void* __restrict__ Wv,
    const float* __restrict__ bq, const float* __restrict__ bk,
    const float* __restrict__ bv,
    short* __restrict__ Qo, short* __restrict__ Ko, short* __restrict__ Vo)
{
    __shared__ short As[128 * 32];   // unpadded: required by global_load_lds
    __shared__ short Bs[128 * 32];

    const int z = blockIdx.z;
    const void* Xv = (z == 0) ? dec : enc;
    const void* Wp_ = (z == 0) ? Wq : (z == 1) ? Wk : Wv;
    const float* bias = (z == 0) ? bq : (z == 1) ? bk : bv;
    short* Yo = (z == 0) ? Qo : (z == 1) ? Ko : Vo;

    const int t = threadIdx.x;
    const int lane = t & 63, wv = t >> 6;
    const int lr = lane & 15, quad = lane >> 4;
    const int wm = wv >> 1, wn = wv & 1;
    const int m0 = blockIdx.y * 128;
    const int n0 = blockIdx.x * 128;
    const int K = DD;

    f32x4 acc[4][4];
    #pragma unroll
    for (int i = 0; i < 4; i++)
        #pragma unroll
        for (int j = 0; j < 4; j++) acc[i][j] = (f32x4){0.f, 0.f, 0.f, 0.f};

    for (int kb = 0; kb < K; kb += 32) {
        __syncthreads();
        if (BF) {
            const short* Xb = (const short*)Xv;
            const short* Wb = (const short*)Wp_;
            #pragma unroll
            for (int c = 0; c < 2; c++) {
                int r0 = wv * 32 + c * 16;              // 16 rows x 64B = 1KB/call
                int r = r0 + (lane >> 2), ch = (lane & 3) * 8;
                GLL(Xb + (size_t)(m0 + r) * K + kb + ch, &As[r0 * 32]);
                GLL(Wb + (size_t)(n0 + r) * K + kb + ch, &Bs[r0 * 32]);
            }
        } else {
            const float* Xf = (const float*)Xv;
            const float* Wf = (const float*)Wp_;
            #pragma unroll
            for (int c = 0; c < 2; c++) {
                int id = t + c * 256;
                int r = id >> 2, c8 = (id & 3) * 8;
                *(bf16x8*)&As[r * 32 + c8] = cvt8(Xf + (size_t)(m0 + r) * K + kb + c8);
                *(bf16x8*)&Bs[r * 32 + c8] = cvt8(Wf + (size_t)(n0 + r) * K + kb + c8);
            }
        }
        __syncthreads();

        bf16x8 af[4], bfr[4];
        #pragma unroll
        for (int mi = 0; mi < 4; mi++)
            af[mi] = *(const bf16x8*)&As[(wm * 64 + mi * 16 + lr) * 32 + quad * 8];
        #pragma unroll
        for (int ni = 0; ni < 4; ni++)
            bfr[ni] = *(const bf16x8*)&Bs[(wn * 64 + ni * 16 + lr) * 32 + quad * 8];
        #pragma unroll
        for (int mi = 0; mi < 4; mi++)
            #pragma unroll
            for (int ni = 0; ni < 4; ni++)
                acc[mi][ni] = __builtin_amdgcn_mfma_f32_16x16x32_bf16(
                    af[mi], bfr[ni], acc[mi][ni], 0, 0, 0);
    }

    if (z < 2) {
        #pragma unroll
        for (int ni = 0; ni < 4; ni++) {
            int col = n0 + wn * 64 + ni * 16 + lr;
            int h = col >> 6, hd = col & 63;
            float bvv = bias[col];
            #pragma unroll
            for (int mi = 0; mi < 4; mi++) {
                #pragma unroll
                for (int r2 = 0; r2 < 4; r2++) {
                    int row = m0 + wm * 64 + mi * 16 + quad * 4 + r2;
                    int b = row >> 11, s = row & 2047;
                    float v = acc[mi][ni][r2] + bvv;
                    size_t off = ((size_t)(b * HH + h) * SS + s) * HD + hd;
                    Yo[off] = f2bf_fast(v);
                }
            }
        }
    } else {
        // V: r2 indexes consecutive s -> pack 4 bf16 = 8B contiguous stores
        #pragma unroll
        for (int ni = 0; ni < 4; ni++) {
            int col = n0 + wn * 64 + ni * 16 + lr;
            int h = col >> 6, hd = col & 63;
            float bvv = bias[col];
            #pragma unroll
            for (int mi = 0; mi < 4; mi++) {
                int s0 = m0 + wm * 64 + mi * 16 + quad * 4;
                int b = s0 >> 11, s = s0 & 2047;
                union { uint32_t d[2]; } u;
                u.d[0] = pack_bf2(acc[mi][ni][0] + bvv, acc[mi][ni][1] + bvv);
                u.d[1] = pack_bf2(acc[mi][ni][2] + bvv, acc[mi][ni][3] + bvv);
                size_t off = ((size_t)(b * HH + h) * HD + hd) * SS + s;
                *(uint2*)(Yo + off) = *(uint2*)&u;
            }
        }
    }
}

// ---------------- output projection: 64x128 tile (512 blocks = 2/CU) -------
template<int WBF>
__global__ __launch_bounds__(256, 2) void proj_gemm_kernel(
    const short* __restrict__ X,
    const void* __restrict__ W, const float* __restrict__ bias,
    float* __restrict__ Y)
{
    __shared__ short As[64 * 32];
    __shared__ short Bs[128 * 32];

    const int t = threadIdx.x;
    const int lane = t & 63, wv = t >> 6;
    const int lr = lane & 15, quad = lane >> 4;
    const int wm = wv >> 1, wn = wv & 1;
    const int m0 = blockIdx.y * 64;
    const int n0 = blockIdx.x * 128;
    const int K = DD, N = DD;

    f32x4 acc[2][4];
    #pragma unroll
    for (int i = 0; i < 2; i++)
        #pragma unroll
        for (int j = 0; j < 4; j++) acc[i][j] = (f32x4){0.f, 0.f, 0.f, 0.f};

    for (int kb = 0; kb < K; kb += 32) {
        __syncthreads();
        {   // A: 4KB total, 1 call/wave (16 rows)
            int r0 = wv * 16;
            int r = r0 + (lane >> 2), ch = (lane & 3) * 8;
            GLL(X + (size_t)(m0 + r) * K + kb + ch, &As[r0 * 32]);
        }
        if (WBF) {
            const short* Wb = (const short*)W;
            #pragma unroll
            for (int c = 0; c < 2; c++) {
                int r0 = wv * 32 + c * 16;
                int r = r0 + (lane >> 2), ch = (lane & 3) * 8;
                GLL(Wb + (size_t)(n0 + r) * K + kb + ch, &Bs[r0 * 32]);
            }
        } else {
            const float* Wf = (const float*)W;
            #pragma unroll
            for (int c = 0; c < 2; c++) {
                int id = t + c * 256;
                int r = id >> 2, c8 = (id & 3) * 8;
                *(bf16x8*)&Bs[r * 32 + c8] = cvt8(Wf + (size_t)(n0 + r) * K + kb + c8);
            }
        }
        __syncthreads();

        bf16x8 af[2], bfr[4];
        #pragma unroll
        for (int mi = 0; mi < 2; mi++)
            af[mi] = *(const bf16x8*)&As[(wm * 32 + mi * 16 + lr) * 32 + quad * 8];
        #pragma unroll
        for (int ni = 0; ni < 4; ni++)
            bfr[ni] = *(const bf16x8*)&Bs[(wn * 64 + ni * 16 + lr) * 32 + quad * 8];
        #pragma unroll
        for (int mi = 0; mi < 2; mi++)
            #pragma unroll
            for (int ni = 0; ni < 4; ni++)
                acc[mi][ni] = __builtin_amdgcn_mfma_f32_16x16x32_bf16(
                    af[mi], bfr[ni], acc[mi][ni], 0, 0, 0);
    }

    #pragma unroll
    for (int ni = 0; ni < 4; ni++) {
        int col = n0 + wn * 64 + ni * 16 + lr;
        float bvv = bias[col];
        #pragma unroll
        for (int mi = 0; mi < 2; mi++) {
            #pragma unroll
            for (int r2 = 0; r2 < 4; r2++) {
                int row = m0 + wm * 32 + mi * 16 + quad * 4 + r2;
                Y[(size_t)row * N + col] = acc[mi][ni][r2] + bvv;
            }
        }
    }
}

// ---------------- flash attention, 32 queries/wave, register P --------------
// Q,K: [B*H, S, HD] bf16.  Vt_g: [B*H, HD, S] bf16.  Y: [B, S, D] bf16.
// This revision:
//  * K/V staged via global_load_lds with PRE-SWIZZLED global source addrs
//    (16B-chunk XOR swizzle: chunk ^= row&7) -> conflict-free ds reads AND
//    no VGPR round-trip / ds_write pass.
//  * Double-buffered LDS (64KB), GLLs for tile kt+1 issued before compute
//    of tile kt, ONE barrier per iter -> HBM latency hidden under compute.
//  * XCD-aware block remap: the 16 query-tiles sharing one bh's K/V land on
//    the same XCD (4 bh-groups x 512KB = 2MB < 4MB L2/XCD).
__global__ __launch_bounds__(256, 2) void attn_kernel(
    const short* __restrict__ Q,
    const short* __restrict__ Kgl,
    const short* __restrict__ Vt_g,
    short* __restrict__ Y)
{
    __shared__ short Ks[2][128][64];   // [buf][key][hd], chunk-XOR swizzled
    __shared__ short Vt[2][64][128];   // [buf][hd][key], chunk-XOR swizzled

    const int t = threadIdx.x;
    const int lane = t & 63, w = t >> 6;
    const int lr = lane & 15, quad = lane >> 4;
    const int e = lr & 7;              // row-XOR term for swizzled reads

    // XCD-aware remap: xcd = bid%8 (round-robin heuristic); each XCD gets
    // 4 whole bh groups (16 qt each). Bijective: 512 = 8 * 64.
    const int bid = blockIdx.x;
    const int slot = bid >> 3;             // 0..63 within XCD
    const int bh = ((slot >> 4) << 3) + (bid & 7);
    const int qt = slot & 15;
    const int b = bh >> 4, h = bh & 15;

    const float C = 0.125f * 1.44269504088896f;  // scale * log2(e)

    // two query groups per wave: qA = qt*128 + w*32 + lr, qB = qA + 16
    const short* QpA = Q + ((size_t)bh * SS + qt * 128 + w * 32 + lr) * HD;
    const short* QpB = QpA + 16 * HD;
    bf16x8 qfA0 = *(const bf16x8*)(QpA + quad * 8);
    bf16x8 qfA1 = *(const bf16x8*)(QpA + 32 + quad * 8);
    bf16x8 qfB0 = *(const bf16x8*)(QpB + quad * 8);
    bf16x8 qfB1 = *(const bf16x8*)(QpB + 32 + quad * 8);

    f32x4 oA[4], oB[4];   // O^T: d = dt*16 + quad*4 + reg, q = lr
    #pragma unroll
    for (int i = 0; i < 4; i++) {
        oA[i] = (f32x4){0.f, 0.f, 0.f, 0.f};
        oB[i] = (f32x4){0.f, 0.f, 0.f, 0.f};
    }
    float lsumA = 0.f, lsumB = 0.f;

    const short* Kb = Kgl + (size_t)bh * SS * HD;
    const short* Vb = Vt_g + (size_t)bh * HD * SS;

    // stage tile kt1 into buffer nb (per wave: 4KB of K + 4KB of V)
    // K dest chunk (l&7) of row r0+(l>>3) holds source chunk (l&7)^(r&7)
    // V dest chunk (l&15) of row h0+(l>>4) holds source chunk (l&15)^(hd&7)
    auto stage = [&](int kt1, int nb) {
        #pragma unroll
        for (int c = 0; c < 4; c++) {
            int r0 = w * 32 + c * 8;
            int r  = r0 + (lane >> 3);
            int sc = ((lane & 7) ^ (r & 7)) * 8;
            GLL(Kb + (size_t)(kt1 * 128 + r) * 64 + sc, &Ks[nb][r0][0]);
        }
        #pragma unroll
        for (int c = 0; c < 4; c++) {
            int h0 = w * 16 + c * 4;
            int hd = h0 + (lane >> 4);
            int s16 = (lane & 15) ^ (hd & 7);
            GLL(Vb + (size_t)hd * SS + kt1 * 128 + s16 * 8, &Vt[nb][h0][0]);
        }
    };

    stage(0, 0);
    __syncthreads();

    int cur = 0;
    for (int kt = 0; kt < SS / 128; kt++) {
        // issue next tile's loads; they drain at this iter's end barrier
        if (kt + 1 < SS / 128) stage(kt + 1, cur ^ 1);

        // S^T = K @ Q^T over 128 keys; each kf read feeds both query groups
        f32x4 scA[8], scB[8];
        #pragma unroll
        for (int nt = 0; nt < 8; nt++) {
            const short* krow = &Ks[cur][nt * 16 + lr][0];
            bf16x8 kf0 = *(const bf16x8*)&krow[(quad ^ e) * 8];
            bf16x8 kf1 = *(const bf16x8*)&krow[((quad + 4) ^ e) * 8];
            scA[nt] = __builtin_amdgcn_mfma_f32_16x16x32_bf16(
                kf0, qfA0, (f32x4){0.f, 0.f, 0.f, 0.f}, 0, 0, 0);
            scA[nt] = __builtin_amdgcn_mfma_f32_16x16x32_bf16(kf1, qfA1, scA[nt], 0, 0, 0);
            scB[nt] = __builtin_amdgcn_mfma_f32_16x16x32_bf16(
                kf0, qfB0, (f32x4){0.f, 0.f, 0.f, 0.f}, 0, 0, 0);
            scB[nt] = __builtin_amdgcn_mfma_f32_16x16x32_bf16(kf1, qfB1, scB[nt], 0, 0, 0);
        }

        // P^T = exp2(S^T * C) in registers -> 16x16x16 B-frags
        bf16x4 pbA[8], pbB[8];
        #pragma unroll
        for (int nt = 0; nt < 8; nt++) {
            float a0 = __builtin_amdgcn_exp2f(scA[nt][0] * C);
            float a1 = __builtin_amdgcn_exp2f(scA[nt][1] * C);
            float a2 = __builtin_amdgcn_exp2f(scA[nt][2] * C);
            float a3 = __builtin_amdgcn_exp2f(scA[nt][3] * C);
            lsumA += (a0 + a1) + (a2 + a3);
            union { uint32_t d[2]; bf16x4 v; } ua;
            ua.d[0] = pack_bf2(a0, a1);
            ua.d[1] = pack_bf2(a2, a3);
            pbA[nt] = ua.v;
            float b0 = __builtin_amdgcn_exp2f(scB[nt][0] * C);
            float b1 = __builtin_amdgcn_exp2f(scB[nt][1] * C);
            float b2 = __builtin_amdgcn_exp2f(scB[nt][2] * C);
            float b3 = __builtin_amdgcn_exp2f(scB[nt][3] * C);
            lsumB += (b0 + b1) + (b2 + b3);
            union { uint32_t d[2]; bf16x4 v; } ub;
            ub.d[0] = pack_bf2(b0, b1);
            ub.d[1] = pack_bf2(b2, b3);
            pbB[nt] = ub.v;
        }

        // O^T += V^T @ P^T ; each va read feeds both groups
        #pragma unroll
        for (int dt = 0; dt < 4; dt++) {
            const short* vrow = &Vt[cur][dt * 16 + lr][0];
            #pragma unroll
            for (int nt = 0; nt < 8; nt++) {
                int ch = (nt * 2 + (quad >> 1)) ^ e;
                bf16x4 va = *(const bf16x4*)&vrow[ch * 8 + (quad & 1) * 4];
                oA[dt] = MFMA16(va, pbA[nt], oA[dt]);
                oB[dt] = MFMA16(va, pbB[nt], oB[dt]);
            }
        }

        __syncthreads();   // GLLs for kt+1 drained; prior buf reads done
        cur ^= 1;
    }

    // full row-sums: combine the 4 quads holding q=lr
    lsumA += __shfl_xor(lsumA, 16, 64);
    lsumA += __shfl_xor(lsumA, 32, 64);
    lsumB += __shfl_xor(lsumB, 16, 64);
    lsumB += __shfl_xor(lsumB, 32, 64);
    float invA = 1.0f / lsumA, invB = 1.0f / lsumB;

    // O^T -> Y[b][s=q][h*64+d]; 4 consecutive d per lane -> 8B stores
    const int srowA = qt * 128 + w * 32 + lr;
    short* YpA = Y + ((size_t)b * SS + srowA) * DD + h * 64 + quad * 4;
    short* YpB = YpA + 16 * DD;
    #pragma unroll
    for (int dt = 0; dt < 4; dt++) {
        union { uint32_t d[2]; } ua;
        ua.d[0] = pack_bf2(oA[dt][0] * invA, oA[dt][1] * invA);
        ua.d[1] = pack_bf2(oA[dt][2] * invA, oA[dt][3] * invA);
        *(uint2*)(YpA + dt * 16) = *(uint2*)&ua;
        union { uint32_t d[2]; } ub;
        ub.d[0] = pack_bf2(oB[dt][0] * invB, oB[dt][1] * invB);
        ub.d[1] = pack_bf2(oB[dt][2] * invB, oB[dt][3] * invB);
        *(uint2*)(YpB + dt * 16) = *(uint2*)&ub;
    }
}

extern "C" void kernel_launch(void* const* d_in, const int* in_sizes, int n_in,
                              void* d_out, int out_size, void* d_ws, size_t ws_size,
                              hipStream_t stream) {
    const float* dec = (const float*)d_in[0];
    const float* enc = (const float*)d_in[1];
    const float* Wq  = (const float*)d_in[2];
    const float* bq  = (const float*)d_in[3];
    const float* Wk  = (const float*)d_in[4];
    const float* bk  = (const float*)d_in[5];
    const float* Wv  = (const float*)d_in[6];
    const float* bv  = (const float*)d_in[7];
    const float* Wp  = (const float*)d_in[8];
    const float* bp  = (const float*)d_in[9];

    const size_t per = (size_t)BB * HH * SS * HD;  // 4,194,304
    const size_t wsz = (size_t)DD * DD;            // 1,048,576
    short* ws = (short*)d_ws;
    short* Qb  = ws;
    short* Kb  = ws + per;
    short* Vtb = ws + 2 * per;
    short* Yb  = ws + 3 * per;

    dim3 qkv_grid(DD / 128, (BB * SS) / 128, 3);   // 768 blocks = 3/CU
    dim3 proj_grid(DD / 128, (BB * SS) / 64);      // 512 blocks = 2/CU
    const int attn_blocks = BB * HH * (SS / 128);  // 512 = 2/CU

    const size_t need = (6 * per + 4 * wsz) * sizeof(short);
    if (ws_size >= need) {
        short* decb = ws + 4 * per;
        short* encb = ws + 5 * per;
        short* Wqb  = ws + 6 * per;
        short* Wkb  = Wqb + wsz;
        short* Wvb  = Wqb + 2 * wsz;
        short* Wpb  = Wqb + 3 * wsz;
        cvt6_kernel<<<dim3((BB * SS * DD / 8 + 255) / 256, 1, 6), 256, 0, stream>>>(
            dec, enc, Wq, Wk, Wv, Wp, decb, encb, Wqb, Wkb, Wvb, Wpb);
        qkv_gemm_kernel<1><<<qkv_grid, 256, 0, stream>>>(
            decb, encb, Wqb, Wkb, Wvb, bq, bk, bv, Qb, Kb, Vtb);
        attn_kernel<<<attn_blocks, 256, 0, stream>>>(Qb, Kb, Vtb, Yb);
        proj_gemm_kernel<1><<<proj_grid, 256, 0, stream>>>(Yb, Wpb, bp, (float*)d_out);
    } else {
        qkv_gemm_kernel<0><<<qkv_grid, 256, 0, stream>>>(
            dec, enc, Wq, Wk, Wv, bq, bk, bv, Qb, Kb, Vtb);
        attn_kernel<<<attn_blocks, 256, 0, stream>>>(Qb, Kb, Vtb, Yb);
        proj_gemm_kernel<0><<<proj_grid, 256, 0, stream>>>(Yb, Wp, bp, (float*)d_out);
    }
}

// Round 2
// 204.153 us; speedup vs baseline: 1.0573x; 1.0399x over previous
//
#include <hip/hip_runtime.h>
#include <hip/hip_bf16.h>
#include <cstdint>
#include <cstddef>

// Problem constants
#define BB 2
#define SS 2048
#define DD 1024
#define HH 16
#define HD 64

typedef __attribute__((ext_vector_type(8))) short bf16x8;
typedef __attribute__((ext_vector_type(4))) short bf16x4;
typedef __attribute__((ext_vector_type(4))) float f32x4;

// 16x16x16 bf16 MFMA (canonical _1k spelling; 4 bf16 per A/B operand)
#define MFMA16(va, vb, c) __builtin_amdgcn_mfma_f32_16x16x16bf16_1k(va, vb, c, 0, 0, 0)

// async global->LDS, 16B per lane, dest = wave-uniform base + lane*16
#define GLL(g, l) __builtin_amdgcn_global_load_lds( \
    (const __attribute__((address_space(1))) void*)(g), \
    (__attribute__((address_space(3))) void*)(l), 16, 0, 0)

// fast RTNE f32->bf16 (inputs guaranteed non-NaN in this problem)
__device__ __forceinline__ short f2bf_fast(float f) {
    uint32_t u = __float_as_uint(f);
    u += 0x7FFF + ((u >> 16) & 1);
    return (short)(u >> 16);
}
__device__ __forceinline__ uint32_t pack_bf2(float a, float b) {
    uint32_t ua = __float_as_uint(a), ub = __float_as_uint(b);
    ua += 0x7FFF + ((ua >> 16) & 1);
    ub += 0x7FFF + ((ub >> 16) & 1);
    return (ua >> 16) | (ub & 0xFFFF0000u);
}
// single-instruction RTNE pack of 2 f32 -> 2 bf16 (bit-identical to pack_bf2)
__device__ __forceinline__ uint32_t cvtpk_bf2(float a, float b) {
    uint32_t r;
    asm("v_cvt_pk_bf16_f32 %0, %1, %2" : "=v"(r) : "v"(a), "v"(b));
    return r;
}
// 8 fp32 -> 8 bf16 via two float4 loads, packed
__device__ __forceinline__ bf16x8 cvt8(const float* __restrict__ p) {
    float4 a = *(const float4*)p;
    float4 b = *(const float4*)(p + 4);
    union { uint32_t d[4]; bf16x8 v; } r;
    r.d[0] = pack_bf2(a.x, a.y);
    r.d[1] = pack_bf2(a.z, a.w);
    r.d[2] = pack_bf2(b.x, b.y);
    r.d[3] = pack_bf2(b.z, b.w);
    return r.v;
}

// ---------------- fp32 -> bf16 pre-convert (6 tensors, one dispatch) --------
__global__ __launch_bounds__(256) void cvt6_kernel(
    const float* __restrict__ s0, const float* __restrict__ s1,
    const float* __restrict__ s2, const float* __restrict__ s3,
    const float* __restrict__ s4, const float* __restrict__ s5,
    short* __restrict__ d0, short* __restrict__ d1, short* __restrict__ d2,
    short* __restrict__ d3, short* __restrict__ d4, short* __restrict__ d5)
{
    const int z = blockIdx.z;
    const float* s = (z == 0) ? s0 : (z == 1) ? s1 : (z == 2) ? s2
                   : (z == 3) ? s3 : (z == 4) ? s4 : s5;
    short* d = (z == 0) ? d0 : (z == 1) ? d1 : (z == 2) ? d2
             : (z == 3) ? d3 : (z == 4) ? d4 : d5;
    const int n8 = (z < 2) ? (BB * SS * DD / 8) : (DD * DD / 8);
    const int id = blockIdx.x * 256 + threadIdx.x;
    if (id >= n8) return;
    bf16x8 r = cvt8(s + (size_t)id * 8);
    *(uint4*)(d + (size_t)id * 8) = *(uint4*)&r;
}

// ---------------- fused QKV GEMM: 128x128 tile, z selects Q/K/V -------------
// z=0: Q -> [B,H,S,HD] (PRE-SCALED by 0.125*log2e for softmax exp2);
// z=1: K -> [B,H,S,HD]; z=2: V -> [B,H,HD,S] (transposed)
template<int BF>
__global__ __launch_bounds__(256, 3) void qkv_gemm_kernel(
    const void* __restrict__ dec, const void* __restrict__ enc,
    const void* __restrict__ Wq, const void* __restrict__ Wk,
    const void* __restrict__ Wv,
    const float* __restrict__ bq, const float* __restrict__ bk,
    const float* __restrict__ bv,
    short* __restrict__ Qo, short* __restrict__ Ko, short* __restrict__ Vo)
{
    __shared__ short As[128 * 32];   // unpadded: required by global_load_lds
    __shared__ short Bs[128 * 32];

    const int z = blockIdx.z;
    const void* Xv = (z == 0) ? dec : enc;
    const void* Wp_ = (z == 0) ? Wq : (z == 1) ? Wk : Wv;
    const float* bias = (z == 0) ? bq : (z == 1) ? bk : bv;
    short* Yo = (z == 0) ? Qo : (z == 1) ? Ko : Vo;
    // fold softmax scale*log2(e) into Q (mul happens in f32 BEFORE the single
    // bf16 rounding -> same rounding count as before, numerics ~identical)
    const float qs = (z == 0) ? (0.125f * 1.44269504088896f) : 1.0f;

    const int t = threadIdx.x;
    const int lane = t & 63, wv = t >> 6;
    const int lr = lane & 15, quad = lane >> 4;
    const int wm = wv >> 1, wn = wv & 1;
    const int m0 = blockIdx.y * 128;
    const int n0 = blockIdx.x * 128;
    const int K = DD;

    f32x4 acc[4][4];
    #pragma unroll
    for (int i = 0; i < 4; i++)
        #pragma unroll
        for (int j = 0; j < 4; j++) acc[i][j] = (f32x4){0.f, 0.f, 0.f, 0.f};

    for (int kb = 0; kb < K; kb += 32) {
        __syncthreads();
        if (BF) {
            const short* Xb = (const short*)Xv;
            const short* Wb = (const short*)Wp_;
            #pragma unroll
            for (int c = 0; c < 2; c++) {
                int r0 = wv * 32 + c * 16;              // 16 rows x 64B = 1KB/call
                int r = r0 + (lane >> 2), ch = (lane & 3) * 8;
                GLL(Xb + (size_t)(m0 + r) * K + kb + ch, &As[r0 * 32]);
                GLL(Wb + (size_t)(n0 + r) * K + kb + ch, &Bs[r0 * 32]);
            }
        } else {
            const float* Xf = (const float*)Xv;
            const float* Wf = (const float*)Wp_;
            #pragma unroll
            for (int c = 0; c < 2; c++) {
                int id = t + c * 256;
                int r = id >> 2, c8 = (id & 3) * 8;
                *(bf16x8*)&As[r * 32 + c8] = cvt8(Xf + (size_t)(m0 + r) * K + kb + c8);
                *(bf16x8*)&Bs[r * 32 + c8] = cvt8(Wf + (size_t)(n0 + r) * K + kb + c8);
            }
        }
        __syncthreads();

        bf16x8 af[4], bfr[4];
        #pragma unroll
        for (int mi = 0; mi < 4; mi++)
            af[mi] = *(const bf16x8*)&As[(wm * 64 + mi * 16 + lr) * 32 + quad * 8];
        #pragma unroll
        for (int ni = 0; ni < 4; ni++)
            bfr[ni] = *(const bf16x8*)&Bs[(wn * 64 + ni * 16 + lr) * 32 + quad * 8];
        #pragma unroll
        for (int mi = 0; mi < 4; mi++)
            #pragma unroll
            for (int ni = 0; ni < 4; ni++)
                acc[mi][ni] = __builtin_amdgcn_mfma_f32_16x16x32_bf16(
                    af[mi], bfr[ni], acc[mi][ni], 0, 0, 0);
    }

    if (z < 2) {
        #pragma unroll
        for (int ni = 0; ni < 4; ni++) {
            int col = n0 + wn * 64 + ni * 16 + lr;
            int h = col >> 6, hd = col & 63;
            float bvv = bias[col];
            #pragma unroll
            for (int mi = 0; mi < 4; mi++) {
                #pragma unroll
                for (int r2 = 0; r2 < 4; r2++) {
                    int row = m0 + wm * 64 + mi * 16 + quad * 4 + r2;
                    int b = row >> 11, s = row & 2047;
                    float v = (acc[mi][ni][r2] + bvv) * qs;
                    size_t off = ((size_t)(b * HH + h) * SS + s) * HD + hd;
                    Yo[off] = f2bf_fast(v);
                }
            }
        }
    } else {
        // V: r2 indexes consecutive s -> pack 4 bf16 = 8B contiguous stores
        #pragma unroll
        for (int ni = 0; ni < 4; ni++) {
            int col = n0 + wn * 64 + ni * 16 + lr;
            int h = col >> 6, hd = col & 63;
            float bvv = bias[col];
            #pragma unroll
            for (int mi = 0; mi < 4; mi++) {
                int s0 = m0 + wm * 64 + mi * 16 + quad * 4;
                int b = s0 >> 11, s = s0 & 2047;
                union { uint32_t d[2]; } u;
                u.d[0] = pack_bf2(acc[mi][ni][0] + bvv, acc[mi][ni][1] + bvv);
                u.d[1] = pack_bf2(acc[mi][ni][2] + bvv, acc[mi][ni][3] + bvv);
                size_t off = ((size_t)(b * HH + h) * HD + hd) * SS + s;
                *(uint2*)(Yo + off) = *(uint2*)&u;
            }
        }
    }
}

// ---------------- output projection: 64x128 tile (512 blocks = 2/CU) -------
template<int WBF>
__global__ __launch_bounds__(256, 2) void proj_gemm_kernel(
    const short* __restrict__ X,
    const void* __restrict__ W, const float* __restrict__ bias,
    float* __restrict__ Y)
{
    __shared__ short As[64 * 32];
    __shared__ short Bs[128 * 32];

    const int t = threadIdx.x;
    const int lane = t & 63, wv = t >> 6;
    const int lr = lane & 15, quad = lane >> 4;
    const int wm = wv >> 1, wn = wv & 1;
    const int m0 = blockIdx.y * 64;
    const int n0 = blockIdx.x * 128;
    const int K = DD, N = DD;

    f32x4 acc[2][4];
    #pragma unroll
    for (int i = 0; i < 2; i++)
        #pragma unroll
        for (int j = 0; j < 4; j++) acc[i][j] = (f32x4){0.f, 0.f, 0.f, 0.f};

    for (int kb = 0; kb < K; kb += 32) {
        __syncthreads();
        {   // A: 4KB total, 1 call/wave (16 rows)
            int r0 = wv * 16;
            int r = r0 + (lane >> 2), ch = (lane & 3) * 8;
            GLL(X + (size_t)(m0 + r) * K + kb + ch, &As[r0 * 32]);
        }
        if (WBF) {
            const short* Wb = (const short*)W;
            #pragma unroll
            for (int c = 0; c < 2; c++) {
                int r0 = wv * 32 + c * 16;
                int r = r0 + (lane >> 2), ch = (lane & 3) * 8;
                GLL(Wb + (size_t)(n0 + r) * K + kb + ch, &Bs[r0 * 32]);
            }
        } else {
            const float* Wf = (const float*)W;
            #pragma unroll
            for (int c = 0; c < 2; c++) {
                int id = t + c * 256;
                int r = id >> 2, c8 = (id & 3) * 8;
                *(bf16x8*)&Bs[r * 32 + c8] = cvt8(Wf + (size_t)(n0 + r) * K + kb + c8);
            }
        }
        __syncthreads();

        bf16x8 af[2], bfr[4];
        #pragma unroll
        for (int mi = 0; mi < 2; mi++)
            af[mi] = *(const bf16x8*)&As[(wm * 32 + mi * 16 + lr) * 32 + quad * 8];
        #pragma unroll
        for (int ni = 0; ni < 4; ni++)
            bfr[ni] = *(const bf16x8*)&Bs[(wn * 64 + ni * 16 + lr) * 32 + quad * 8];
        #pragma unroll
        for (int mi = 0; mi < 2; mi++)
            #pragma unroll
            for (int ni = 0; ni < 4; ni++)
                acc[mi][ni] = __builtin_amdgcn_mfma_f32_16x16x32_bf16(
                    af[mi], bfr[ni], acc[mi][ni], 0, 0, 0);
    }

    #pragma unroll
    for (int ni = 0; ni < 4; ni++) {
        int col = n0 + wn * 64 + ni * 16 + lr;
        float bvv = bias[col];
        #pragma unroll
        for (int mi = 0; mi < 2; mi++) {
            #pragma unroll
            for (int r2 = 0; r2 < 4; r2++) {
                int row = m0 + wm * 32 + mi * 16 + quad * 4 + r2;
                Y[(size_t)row * N + col] = acc[mi][ni][r2] + bvv;
            }
        }
    }
}

// ---------------- flash attention, 32 queries/wave, register P --------------
// Q,K: [B*H, S, HD] bf16 (Q pre-scaled by 0.125*log2e).  Vt_g: [B*H, HD, S].
// Softmax VALU minimized: no per-score mul (Q pre-scaled), single-instr
// v_cvt_pk_bf16_f32 pack, f32x4 vector sum accumulators (v_pk_add_f32).
// s_setprio(1) wraps both MFMA clusters (T5: wave role diversity exists here).
__global__ __launch_bounds__(256, 2) void attn_kernel(
    const short* __restrict__ Q,
    const short* __restrict__ Kgl,
    const short* __restrict__ Vt_g,
    short* __restrict__ Y)
{
    __shared__ short Ks[2][128][64];   // [buf][key][hd], chunk-XOR swizzled
    __shared__ short Vt[2][64][128];   // [buf][hd][key], chunk-XOR swizzled

    const int t = threadIdx.x;
    const int lane = t & 63, w = t >> 6;
    const int lr = lane & 15, quad = lane >> 4;
    const int e = lr & 7;              // row-XOR term for swizzled reads

    // XCD-aware remap: each XCD gets 4 whole bh groups (16 qt each).
    const int bid = blockIdx.x;
    const int slot = bid >> 3;             // 0..63 within XCD
    const int bh = ((slot >> 4) << 3) + (bid & 7);
    const int qt = slot & 15;
    const int b = bh >> 4, h = bh & 15;

    // two query groups per wave: qA = qt*128 + w*32 + lr, qB = qA + 16
    const short* QpA = Q + ((size_t)bh * SS + qt * 128 + w * 32 + lr) * HD;
    const short* QpB = QpA + 16 * HD;
    bf16x8 qfA0 = *(const bf16x8*)(QpA + quad * 8);
    bf16x8 qfA1 = *(const bf16x8*)(QpA + 32 + quad * 8);
    bf16x8 qfB0 = *(const bf16x8*)(QpB + quad * 8);
    bf16x8 qfB1 = *(const bf16x8*)(QpB + 32 + quad * 8);

    f32x4 oA[4], oB[4];   // O^T: d = dt*16 + quad*4 + reg, q = lr
    #pragma unroll
    for (int i = 0; i < 4; i++) {
        oA[i] = (f32x4){0.f, 0.f, 0.f, 0.f};
        oB[i] = (f32x4){0.f, 0.f, 0.f, 0.f};
    }
    f32x4 vsumA = (f32x4){0.f, 0.f, 0.f, 0.f};
    f32x4 vsumB = (f32x4){0.f, 0.f, 0.f, 0.f};

    const short* Kb = Kgl + (size_t)bh * SS * HD;
    const short* Vb = Vt_g + (size_t)bh * HD * SS;

    // stage tile kt1 into buffer nb (per wave: 4KB of K + 4KB of V)
    auto stage = [&](int kt1, int nb) {
        #pragma unroll
        for (int c = 0; c < 4; c++) {
            int r0 = w * 32 + c * 8;
            int r  = r0 + (lane >> 3);
            int sc = ((lane & 7) ^ (r & 7)) * 8;
            GLL(Kb + (size_t)(kt1 * 128 + r) * 64 + sc, &Ks[nb][r0][0]);
        }
        #pragma unroll
        for (int c = 0; c < 4; c++) {
            int h0 = w * 16 + c * 4;
            int hd = h0 + (lane >> 4);
            int s16 = (lane & 15) ^ (hd & 7);
            GLL(Vb + (size_t)hd * SS + kt1 * 128 + s16 * 8, &Vt[nb][h0][0]);
        }
    };

    stage(0, 0);
    __syncthreads();

    int cur = 0;
    for (int kt = 0; kt < SS / 128; kt++) {
        // issue next tile's loads; they drain at this iter's end barrier
        if (kt + 1 < SS / 128) stage(kt + 1, cur ^ 1);

        // S^T = K @ Q^T over 128 keys; Q carries the softmax scale already
        f32x4 scA[8], scB[8];
        __builtin_amdgcn_s_setprio(1);
        #pragma unroll
        for (int nt = 0; nt < 8; nt++) {
            const short* krow = &Ks[cur][nt * 16 + lr][0];
            bf16x8 kf0 = *(const bf16x8*)&krow[(quad ^ e) * 8];
            bf16x8 kf1 = *(const bf16x8*)&krow[((quad + 4) ^ e) * 8];
            scA[nt] = __builtin_amdgcn_mfma_f32_16x16x32_bf16(
                kf0, qfA0, (f32x4){0.f, 0.f, 0.f, 0.f}, 0, 0, 0);
            scA[nt] = __builtin_amdgcn_mfma_f32_16x16x32_bf16(kf1, qfA1, scA[nt], 0, 0, 0);
            scB[nt] = __builtin_amdgcn_mfma_f32_16x16x32_bf16(
                kf0, qfB0, (f32x4){0.f, 0.f, 0.f, 0.f}, 0, 0, 0);
            scB[nt] = __builtin_amdgcn_mfma_f32_16x16x32_bf16(kf1, qfB1, scB[nt], 0, 0, 0);
        }
        __builtin_amdgcn_s_setprio(0);

        // P^T = exp2(S^T) in registers -> 16x16x16 B-frags
        bf16x4 pbA[8], pbB[8];
        #pragma unroll
        for (int nt = 0; nt < 8; nt++) {
            f32x4 ea, eb;
            ea[0] = __builtin_amdgcn_exp2f(scA[nt][0]);
            ea[1] = __builtin_amdgcn_exp2f(scA[nt][1]);
            ea[2] = __builtin_amdgcn_exp2f(scA[nt][2]);
            ea[3] = __builtin_amdgcn_exp2f(scA[nt][3]);
            vsumA += ea;
            union { uint32_t d[2]; bf16x4 v; } ua;
            ua.d[0] = cvtpk_bf2(ea[0], ea[1]);
            ua.d[1] = cvtpk_bf2(ea[2], ea[3]);
            pbA[nt] = ua.v;
            eb[0] = __builtin_amdgcn_exp2f(scB[nt][0]);
            eb[1] = __builtin_amdgcn_exp2f(scB[nt][1]);
            eb[2] = __builtin_amdgcn_exp2f(scB[nt][2]);
            eb[3] = __builtin_amdgcn_exp2f(scB[nt][3]);
            vsumB += eb;
            union { uint32_t d[2]; bf16x4 v; } ub;
            ub.d[0] = cvtpk_bf2(eb[0], eb[1]);
            ub.d[1] = cvtpk_bf2(eb[2], eb[3]);
            pbB[nt] = ub.v;
        }

        // O^T += V^T @ P^T ; each va read feeds both groups
        __builtin_amdgcn_s_setprio(1);
        #pragma unroll
        for (int dt = 0; dt < 4; dt++) {
            const short* vrow = &Vt[cur][dt * 16 + lr][0];
            #pragma unroll
            for (int nt = 0; nt < 8; nt++) {
                int ch = (nt * 2 + (quad >> 1)) ^ e;
                bf16x4 va = *(const bf16x4*)&vrow[ch * 8 + (quad & 1) * 4];
                oA[dt] = MFMA16(va, pbA[nt], oA[dt]);
                oB[dt] = MFMA16(va, pbB[nt], oB[dt]);
            }
        }
        __builtin_amdgcn_s_setprio(0);

        __syncthreads();   // GLLs for kt+1 drained; prior buf reads done
        cur ^= 1;
    }

    // full row-sums: horizontal + combine the 4 quads holding q=lr
    float lsumA = (vsumA[0] + vsumA[1]) + (vsumA[2] + vsumA[3]);
    float lsumB = (vsumB[0] + vsumB[1]) + (vsumB[2] + vsumB[3]);
    lsumA += __shfl_xor(lsumA, 16, 64);
    lsumA += __shfl_xor(lsumA, 32, 64);
    lsumB += __shfl_xor(lsumB, 16, 64);
    lsumB += __shfl_xor(lsumB, 32, 64);
    float invA = 1.0f / lsumA, invB = 1.0f / lsumB;

    // O^T -> Y[b][s=q][h*64+d]; 4 consecutive d per lane -> 8B stores
    const int srowA = qt * 128 + w * 32 + lr;
    short* YpA = Y + ((size_t)b * SS + srowA) * DD + h * 64 + quad * 4;
    short* YpB = YpA + 16 * DD;
    #pragma unroll
    for (int dt = 0; dt < 4; dt++) {
        union { uint32_t d[2]; } ua;
        ua.d[0] = pack_bf2(oA[dt][0] * invA, oA[dt][1] * invA);
        ua.d[1] = pack_bf2(oA[dt][2] * invA, oA[dt][3] * invA);
        *(uint2*)(YpA + dt * 16) = *(uint2*)&ua;
        union { uint32_t d[2]; } ub;
        ub.d[0] = pack_bf2(oB[dt][0] * invB, oB[dt][1] * invB);
        ub.d[1] = pack_bf2(oB[dt][2] * invB, oB[dt][3] * invB);
        *(uint2*)(YpB + dt * 16) = *(uint2*)&ub;
    }
}

extern "C" void kernel_launch(void* const* d_in, const int* in_sizes, int n_in,
                              void* d_out, int out_size, void* d_ws, size_t ws_size,
                              hipStream_t stream) {
    const float* dec = (const float*)d_in[0];
    const float* enc = (const float*)d_in[1];
    const float* Wq  = (const float*)d_in[2];
    const float* bq  = (const float*)d_in[3];
    const float* Wk  = (const float*)d_in[4];
    const float* bk  = (const float*)d_in[5];
    const float* Wv  = (const float*)d_in[6];
    const float* bv  = (const float*)d_in[7];
    const float* Wp  = (const float*)d_in[8];
    const float* bp  = (const float*)d_in[9];

    const size_t per = (size_t)BB * HH * SS * HD;  // 4,194,304
    const size_t wsz = (size_t)DD * DD;            // 1,048,576
    short* ws = (short*)d_ws;
    short* Qb  = ws;
    short* Kb  = ws + per;
    short* Vtb = ws + 2 * per;
    short* Yb  = ws + 3 * per;

    dim3 qkv_grid(DD / 128, (BB * SS) / 128, 3);   // 768 blocks = 3/CU
    dim3 proj_grid(DD / 128, (BB * SS) / 64);      // 512 blocks = 2/CU
    const int attn_blocks = BB * HH * (SS / 128);  // 512 = 2/CU

    const size_t need = (6 * per + 4 * wsz) * sizeof(short);
    if (ws_size >= need) {
        short* decb = ws + 4 * per;
        short* encb = ws + 5 * per;
        short* Wqb  = ws + 6 * per;
        short* Wkb  = Wqb + wsz;
        short* Wvb  = Wqb + 2 * wsz;
        short* Wpb  = Wqb + 3 * wsz;
        cvt6_kernel<<<dim3((BB * SS * DD / 8 + 255) / 256, 1, 6), 256, 0, stream>>>(
            dec, enc, Wq, Wk, Wv, Wp, decb, encb, Wqb, Wkb, Wvb, Wpb);
        qkv_gemm_kernel<1><<<qkv_grid, 256, 0, stream>>>(
            decb, encb, Wqb, Wkb, Wvb, bq, bk, bv, Qb, Kb, Vtb);
        attn_kernel<<<attn_blocks, 256, 0, stream>>>(Qb, Kb, Vtb, Yb);
        proj_gemm_kernel<1><<<proj_grid, 256, 0, stream>>>(Yb, Wpb, bp, (float*)d_out);
    } else {
        qkv_gemm_kernel<0><<<qkv_grid, 256, 0, stream>>>(
            dec, enc, Wq, Wk, Wv, bq, bk, bv, Qb, Kb, Vtb);
        attn_kernel<<<attn_blocks, 256, 0, stream>>>(Qb, Kb, Vtb, Yb);
        proj_gemm_kernel<0><<<proj_grid, 256, 0, stream>>>(Yb, Wp, bp, (float*)d_out);
    }
}